// Round 12
// baseline (908.481 us; speedup 1.0000x reference)
//
#include <hip/hip_runtime.h>

// VoiceModel: 2 branches x { scalar-LSTM(1->1,L2) over T=512 per (b,class),
// then LSTM(1->256,L2) over 128 class-steps }, concat -> MLP(512->200->128).
// Round 12: round-10 fused kernel with FLAG-FREE self-validating exchange:
// every exchanged f16 carries a freshness stamp in its mantissa LSB. Producers
// fire-and-forget sc1 chunks; consumers gather+validate (retry loop). No flags,
// no push-ack, 2 barriers/step. h0img/ring wiped (sc1) each call.

typedef _Float16 f16;
typedef __attribute__((ext_vector_type(4))) _Float16 f16x4;
typedef __attribute__((ext_vector_type(8))) _Float16 f16x8;
typedef __attribute__((ext_vector_type(4))) float f32x4;
typedef unsigned long long u64;
typedef unsigned short u16;

#define NBATCH 256
#define NTIME  512
#define NCLS   128
#define NHID   256

__device__ __forceinline__ float sigf(float x) {
    return __builtin_amdgcn_rcpf(1.0f + __expf(-x));
}
__device__ __forceinline__ float tanh_f(float x) {
    return fmaf(2.0f, __builtin_amdgcn_rcpf(1.0f + __expf(-2.0f * x)), -1.0f);
}
__device__ __forceinline__ f16x4 LO(f16x8 v) { f16x4 r; r[0]=v[0]; r[1]=v[1]; r[2]=v[2]; r[3]=v[3]; return r; }
__device__ __forceinline__ f16x4 HI(f16x8 v) { f16x4 r; r[0]=v[4]; r[1]=v[5]; r[2]=v[6]; r[3]=v[7]; return r; }

// LLC-coherent (sc1) 8B ops: relaxed agent atomics (proven round 9).
__device__ __forceinline__ u64 ld_llc(const u64* p) {
    return __hip_atomic_load(p, __ATOMIC_RELAXED, __HIP_MEMORY_SCOPE_AGENT);
}
__device__ __forceinline__ void st_llc(u64* p, u64 v) {
    __hip_atomic_store(p, v, __ATOMIC_RELAXED, __HIP_MEMORY_SCOPE_AGENT);
}

// stamped f16: force mantissa LSB to `st` (error <= 1 ULP)
__device__ __forceinline__ f16 stamp16(float x, int st) {
    u16 b = __builtin_bit_cast(u16, (f16)x);
    b = (u16)((b & 0xFFFEu) | (u16)st);
    return __builtin_bit_cast(f16, b);
}

#define STAMP_MASK 0x0001000100010001ull

// gather 7 peer 8B words and retry until each word's 4 stamps match `expect`.
__device__ __forceinline__ void gatherv(const u64* __restrict__ gs,
                                        u64* __restrict__ lds,
                                        const int qm, const int o,
                                        const u64 expect) {
    u64 got[7];
#pragma unroll
    for (int j = 0; j < 7; ++j) {
        const int p = j + (j >= qm);
        got[j] = ld_llc(gs + p * 128 + o);
    }
    unsigned pend = 0x7f;
    while (true) {
        unsigned np = 0;
#pragma unroll
        for (int j = 0; j < 7; ++j)
            if (pend & (1u << j)) {
                if ((got[j] & STAMP_MASK) == expect) {
                    const int p = j + (j >= qm);
                    lds[p * 128 + o] = got[j];
                } else np |= 1u << j;
            }
        pend = np;
        if (!pend) break;
        __builtin_amdgcn_s_sleep(0);
#pragma unroll
        for (int j = 0; j < 7; ++j)
            if (pend & (1u << j)) {
                const int p = j + (j >= qm);
                got[j] = ld_llc(gs + p * 128 + o);
            }
    }
}

// ---------------- K0: convert + swizzle 6 weight matrices (1024x256) to f16 --
// layout per matrix: elem ((g*16+fi)*8+ktp)*512 + l*8 + e   (l = lane)
//   = W[g*256 + fi*16 + fr][ktp*32 + (e>>2)*16 + fq*4 + (e&3)]
struct P6 {
    const float* s0; const float* s1; const float* s2;
    const float* s3; const float* s4; const float* s5;
};

__global__ __launch_bounds__(256) void k_cvt(P6 p, f16* __restrict__ dst) {
    int i = blockIdx.x * 256 + threadIdx.x;      // 6 * 262144 total
    int seg = i >> 18, d = i & 262143;
    const float* s = seg == 0 ? p.s0 : seg == 1 ? p.s1 : seg == 2 ? p.s2
                   : seg == 3 ? p.s3 : seg == 4 ? p.s4 : p.s5;
    const int e  = d & 7;
    const int fr = (d >> 3) & 15;
    const int fq = (d >> 7) & 3;
    const int ktp = (d >> 9) & 7;
    const int fi = (d >> 12) & 15;
    const int g  = (d >> 16) & 3;
    const int row = g * 256 + fi * 16 + fr;
    const int col = ktp * 32 + (e >> 2) * 16 + fq * 4 + (e & 3);
    dst[i] = (f16)s[row * 256 + col];
}

// ---------------- wipe exchange buffers via sc1 (every call; graph-safe) -----
__global__ void k_wipe(u64* __restrict__ p, long n) {
    long i = (long)blockIdx.x * blockDim.x + threadIdx.x;
    const long stride = (long)gridDim.x * blockDim.x;
    for (; i < n; i += stride) st_llc(p + i, 0ull);
}

// ---------------- K1: scalar 2-layer LSTM per (branch, b, class) -------------
__global__ __launch_bounds__(128) void k_scalar_lstm(
    const int* __restrict__ ln, const int* __restrict__ rn,
    const float* __restrict__ tlW, const float* __restrict__ tlU, const float* __restrict__ tlb,
    const float* __restrict__ trW, const float* __restrict__ trU, const float* __restrict__ trb,
    float* __restrict__ states)
{
    __shared__ int tok[NTIME];
    const int bid = blockIdx.x;
    const int branch = bid >> 8;
    const int b = bid & 255;
    const int* tp = (branch ? rn : ln) + (size_t)b * (4 * NTIME);  // voice 0
    for (int i = threadIdx.x; i < NTIME; i += 128) tok[i] = tp[i];
    __syncthreads();
    const float* W  = branch ? trW : tlW;
    const float* U  = branch ? trU : tlU;
    const float* Bb = branch ? trb : tlb;
    const float u00 = U[0], u01 = U[1], u02 = U[2], u03 = U[3];
    const float f00 = Bb[0], f01 = Bb[1], f02 = Bb[2], f03 = Bb[3];
    const float o00 = f00 + W[0], o01 = f01 + W[1], o02 = f02 + W[2], o03 = f03 + W[3];
    const float w10 = W[4], w11 = W[5], w12 = W[6], w13 = W[7];
    const float u10 = U[4], u11 = U[5], u12 = U[6], u13 = U[7];
    const float b10 = Bb[4], b11 = Bb[5], b12 = Bb[6], b13 = Bb[7];
    const int n = threadIdx.x;
    float h0 = 0.f, c0 = 0.f, h1 = 0.f, c1 = 0.f;
    for (int t = 0; t < NTIME; ++t) {
        const bool x = (tok[t] == n);
        float pi = fmaf(u00, h0, x ? o00 : f00);
        float pf = fmaf(u01, h0, x ? o01 : f01);
        float pg = fmaf(u02, h0, x ? o02 : f02);
        float po = fmaf(u03, h0, x ? o03 : f03);
        float ig = sigf(pi), fg = sigf(pf), gg = tanh_f(pg), og = sigf(po);
        c0 = fmaf(fg, c0, ig * gg);
        h0 = og * tanh_f(c0);
        pi = fmaf(w10, h0, fmaf(u10, h1, b10));
        pf = fmaf(w11, h0, fmaf(u11, h1, b11));
        pg = fmaf(w12, h0, fmaf(u12, h1, b12));
        po = fmaf(w13, h0, fmaf(u13, h1, b13));
        ig = sigf(pi); fg = sigf(pf); gg = tanh_f(pg); og = sigf(po);
        c1 = fmaf(fg, c1, ig * gg);
        h1 = og * tanh_f(c1);
    }
    states[((size_t)(branch * NBATCH + b)) * NCLS + n] = h1;
}

// ---------------- K2: FUSED 2-layer recurrence, stamped exchange -------------
// grid 256 = member qm(8) * 32 + group(32). 384 thr = 6 waves.
// role = w>>1: 0 = layer0, 1 = layer1-recurrent, 2 = layer1-input. f = w&1.
// Step s: roles 0 compute h0(s); roles 1+2 compute h1(s-1).
// h0 stamp = 1 (write-once slots, wiped each call); h1 stamp alternates
// ((s>>2)&1)^1 on the depth-4 ring (wiped each call; s=0 pushes stamped zeros).
__global__ __launch_bounds__(384, 1) void k_rec(
    const float* __restrict__ states,
    const f16* __restrict__ whh0, const f16* __restrict__ whh1,
    const f16* __restrict__ wih1,
    const float* __restrict__ wih0L, const float* __restrict__ wih0R,
    const float* __restrict__ b0L, const float* __restrict__ b0R,
    const float* __restrict__ b1L, const float* __restrict__ b1R,
    f16* __restrict__ h0img,               // [32 group][128 s][4096]
    f16* __restrict__ ring,                // [32 group][4 slot][4096]
    float* __restrict__ h1out)             // [2][256][256] f32
{
    extern __shared__ char smem[];
    f16*   wlds0 = (f16*)smem;                   // 65536 B Whh0 slice
    f16*   wlds1 = (f16*)(smem + 65536);         // 65536 B Whh1 slice
    f16*   img0  = (f16*)(smem + 131072);        // 8192 B h0 image
    f16*   img1  = (f16*)(smem + 139264);        // 8192 B h1 image
    float* cmb   = (float*)(smem + 147456);      // 8192 B [2 f][4 g][4 r][64 l]

    const int qm = blockIdx.x >> 5, g = blockIdx.x & 31;
    const int branch = g >> 4, tb = g & 15;
    const int tid = threadIdx.x;
    const int w = tid >> 6, l = tid & 63, fr = l & 15, fq = l >> 4;
    const int role = w >> 1, f = w & 1;
    const int fi = qm * 2 + f;

    {   // stage Whh0 + Whh1 slices (64 rows x 512 f16 each)
        const f16* baseA = whh0 + ((size_t)branch << 18);
        const f16* baseB = whh1 + ((size_t)branch << 18);
        for (int c = tid; c < 8192; c += 384) {
            const int m2 = c >> 12;
            const int rl = (c & 4095) >> 6, coli = c & 63;
            const int gg = rl >> 4, ff = (rl >> 3) & 1, ktp = rl & 7;
            const f16* src = (m2 ? baseB : baseA)
                + ((size_t)((gg * 16 + qm * 2 + ff) * 8 + ktp) << 9) + coli * 8;
            *(uint4*)((m2 ? wlds1 : wlds0) + rl * 512 + coli * 8) = *(const uint4*)src;
        }
    }
    for (int i = tid; i < 512; i += 384) {
        ((uint4*)img0)[i] = (uint4){0u, 0u, 0u, 0u};
        // img1 init = stamped zeros (stamp 1): s=0 push must validate
        ((uint4*)img1)[i] = (uint4){0x00010001u, 0x00010001u, 0x00010001u, 0x00010001u};
    }

    float bv[4], w0v[4];
    {
        const float* b0 = branch ? b0R : b0L;
        const float* b1 = branch ? b1R : b1L;
        const float* w0p = branch ? wih0R : wih0L;
#pragma unroll
        for (int g4 = 0; g4 < 4; ++g4) {
            const int row = g4 * 256 + fi * 16 + fr;
            bv[g4]  = (role == 0) ? b0[row] : b1[row];
            w0v[g4] = (role == 0) ? w0p[row] : 0.f;
        }
    }
    float cst[4] = {0.f, 0.f, 0.f, 0.f};
    const f16* wstream = wih1 + ((size_t)branch << 18) + l * 8;
    f16* gimg = h0img + (size_t)g * (NCLS * 4096);
    f16* gring = ring + (size_t)g * (4 * 4096);
    __syncthreads();

    for (int s = 0; s <= NCLS; ++s) {
        f16* gslot = gring + (size_t)(s & 3) * 4096;
        const int st1 = ((s >> 2) & 1) ^ 1;          // h1 ring stamp this step
        // ---- compute phase --------------------------------------------------
        f32x4 acc[4];
#pragma unroll
        for (int g4 = 0; g4 < 4; ++g4) { f32x4 z = {0.f,0.f,0.f,0.f}; acc[g4] = z; }
        float st[4] = {0.f, 0.f, 0.f, 0.f};
        const bool active = (role == 0) ? (s < NCLS) : (s > 0);
        if (active) {
            f16x4 af[16];
            const f16* srcimg = (role == 1) ? img1 : img0;
#pragma unroll
            for (int kt = 0; kt < 16; ++kt)
                af[kt] = *(const f16x4*)(srcimg + kt * 256 + l * 4);
            if (role == 2) {
#pragma unroll
                for (int g4 = 0; g4 < 4; ++g4) {
                    f16x8 wv[8];
#pragma unroll
                    for (int ktp = 0; ktp < 8; ++ktp)
                        wv[ktp] = *(const f16x8*)(wstream + ((size_t)((g4 * 16 + fi) * 8 + ktp) << 9));
#pragma unroll
                    for (int ktp = 0; ktp < 8; ++ktp) {
                        acc[g4] = __builtin_amdgcn_mfma_f32_16x16x16f16(af[2*ktp],   LO(wv[ktp]), acc[g4], 0, 0, 0);
                        acc[g4] = __builtin_amdgcn_mfma_f32_16x16x16f16(af[2*ktp+1], HI(wv[ktp]), acc[g4], 0, 0, 0);
                    }
                }
#pragma unroll
                for (int g4 = 0; g4 < 4; ++g4)
#pragma unroll
                    for (int r = 0; r < 4; ++r)
                        cmb[(f * 16 + g4 * 4 + r) * 64 + l] = acc[g4][r];
            } else {
                const f16* wl = role ? wlds1 : wlds0;
#pragma unroll
                for (int g4 = 0; g4 < 4; ++g4)
#pragma unroll
                    for (int ktp = 0; ktp < 8; ++ktp) {
                        const f16x8 v = *(const f16x8*)(wl + (((g4 * 2 + f) * 8 + ktp) << 9) + l * 8);
                        acc[g4] = __builtin_amdgcn_mfma_f32_16x16x16f16(af[2*ktp],   LO(v), acc[g4], 0, 0, 0);
                        acc[g4] = __builtin_amdgcn_mfma_f32_16x16x16f16(af[2*ktp+1], HI(v), acc[g4], 0, 0, 0);
                    }
                if (role == 0) {
#pragma unroll
                    for (int r = 0; r < 4; ++r)
                        st[r] = states[((size_t)(branch * NBATCH + tb * 16 + fq * 4 + r)) * NCLS + s];
                }
            }
        }
        __syncthreads();                    // cmb ready; img reads done
        // ---- finish + stamped push (fire-and-forget) + gather-validate ------
        if (role == 0 && s < NCLS) {
#pragma unroll
            for (int r = 0; r < 4; ++r) {
                const float pi = fmaf(st[r], w0v[0], acc[0][r] + bv[0]);
                const float pf = fmaf(st[r], w0v[1], acc[1][r] + bv[1]);
                const float pg = fmaf(st[r], w0v[2], acc[2][r] + bv[2]);
                const float po = fmaf(st[r], w0v[3], acc[3][r] + bv[3]);
                const float ig = sigf(pi), fg = sigf(pf), gg = tanh_f(pg), og = sigf(po);
                cst[r] = fmaf(fg, cst[r], ig * gg);
                const float hn = og * tanh_f(cst[r]);
                img0[fi * 256 + (fq * 4 + r + 16 * (fr >> 2)) * 4 + (fr & 3)] = stamp16(hn, 1);
            }
            asm volatile("s_waitcnt lgkmcnt(0)" ::: "memory");   // frag complete in LDS
            st_llc((u64*)(gimg + (size_t)s * 4096) + fi * 64 + l,
                   ((const u64*)img0)[fi * 64 + l]);             // no ack wait
        } else if (role == 1) {
            if (s > 0) {
                float hn[4];
#pragma unroll
                for (int r = 0; r < 4; ++r) {
                    const float pi = acc[0][r] + cmb[(f * 16 + 0 + r) * 64 + l] + bv[0];
                    const float pf = acc[1][r] + cmb[(f * 16 + 4 + r) * 64 + l] + bv[1];
                    const float pg = acc[2][r] + cmb[(f * 16 + 8 + r) * 64 + l] + bv[2];
                    const float po = acc[3][r] + cmb[(f * 16 + 12 + r) * 64 + l] + bv[3];
                    const float ig = sigf(pi), fg = sigf(pf), gg = tanh_f(pg), og = sigf(po);
                    cst[r] = fmaf(fg, cst[r], ig * gg);
                    hn[r] = og * tanh_f(cst[r]);
                }
                if (s == NCLS) {
#pragma unroll
                    for (int r = 0; r < 4; ++r)
                        h1out[((size_t)(branch * NBATCH + tb * 16 + fq * 4 + r)) * NHID
                              + fi * 16 + fr] = hn[r];
                } else {
#pragma unroll
                    for (int r = 0; r < 4; ++r)
                        img1[fi * 256 + (fq * 4 + r + 16 * (fr >> 2)) * 4 + (fr & 3)] = stamp16(hn[r], st1);
                }
            }
            if (s < NCLS) {
                if (s == 0) {               // re-stamp init zeros for this step (stamp 1 == init ✓)
                    asm volatile("s_waitcnt lgkmcnt(0)" ::: "memory");
                    st_llc((u64*)gslot + fi * 64 + l, ((const u64*)img1)[fi * 64 + l]);
                } else {
                    asm volatile("s_waitcnt lgkmcnt(0)" ::: "memory");
                    st_llc((u64*)gslot + fi * 64 + l, ((const u64*)img1)[fi * 64 + l]);
                }
            }
        }
        if (s == NCLS) break;
        // in-wave gather (same threads that pushed; no barrier needed between)
        if (tid < 128) {                    // roles 0: gather h0(s), stamp 1
            gatherv((const u64*)(gimg + (size_t)s * 4096), (u64*)img0, qm, tid,
                    STAMP_MASK);
        } else if (tid < 256) {             // roles 1: gather h1(s-1), stamp st1
            gatherv((const u64*)gslot, (u64*)img1, qm, tid - 128,
                    st1 ? STAMP_MASK : 0ull);
        }
        __syncthreads();                    // images complete for step s+1
    }
}

// ---------------- K4: MLP head (2H -> 200 -> 128), f32 ------------------------
__global__ __launch_bounds__(256) void k_mlp(
    const float* __restrict__ h1all,   // [2][256][256]
    const float* __restrict__ W1, const float* __restrict__ b1,
    const float* __restrict__ W2, const float* __restrict__ b2,
    float* __restrict__ out)
{
    __shared__ float hrow[512];
    __shared__ float hid[200];
    const int b = blockIdx.x, tid = threadIdx.x;
    hrow[tid]       = h1all[(size_t)b * NHID + tid];
    hrow[256 + tid] = h1all[(size_t)(NBATCH + b) * NHID + tid];
    __syncthreads();
    if (tid < 200) {
        float a = b1[tid];
        const float* wr = W1 + (size_t)tid * 512;
        for (int k = 0; k < 512; ++k) a = fmaf(wr[k], hrow[k], a);
        hid[tid] = fmaxf(a, 0.f);
    }
    __syncthreads();
    if (tid < 128) {
        float a = b2[tid];
        const float* wr = W2 + (size_t)tid * 200;
        for (int j = 0; j < 200; ++j) a = fmaf(wr[j], hid[j], a);
        out[(size_t)b * 128 + tid] = a;
    }
}

// ---------------- launch ------------------------------------------------------
extern "C" void kernel_launch(void* const* d_in, const int* in_sizes, int n_in,
                              void* d_out, int out_size, void* d_ws, size_t ws_size,
                              hipStream_t stream)
{
    (void)in_sizes; (void)n_in; (void)out_size; (void)ws_size;
    const int*   ln    = (const int*)d_in[0];
    const int*   rn    = (const int*)d_in[2];
    const float* tlW   = (const float*)d_in[4];
    const float* tlU   = (const float*)d_in[5];
    const float* tlb   = (const float*)d_in[6];
    const float* trW   = (const float*)d_in[7];
    const float* trU   = (const float*)d_in[8];
    const float* trb   = (const float*)d_in[9];
    const float* wih0L = (const float*)d_in[10];
    const float* b0L   = (const float*)d_in[12];
    const float* b1L   = (const float*)d_in[15];
    const float* wih0R = (const float*)d_in[16];
    const float* b0R   = (const float*)d_in[18];
    const float* b1R   = (const float*)d_in[21];
    const float* mW1   = (const float*)d_in[22];
    const float* mb1   = (const float*)d_in[23];
    const float* mW2   = (const float*)d_in[24];
    const float* mb2   = (const float*)d_in[25];

    // workspace layout (bytes)
    char* ws = (char*)d_ws;
    f16*   w16    = (f16*)ws;                        // 3 MB swizzled weights
    float* states = (float*)(ws + 3145728);          // 256 KB
    float* h1out  = (float*)(ws + 3407872);          // 512 KB
    f16*   ring   = (f16*)(ws + 3932160);            // 1 MB (32 x 4 x 4096 f16)
    f16*   h0img  = (f16*)(ws + 4980736);            // 32 MB (32 x 128 x 4096 f16)
    // wipe region: ring + h0img contiguous = 33 MB

    f16* whh0 = w16;
    f16* whh1 = w16 + 2 * 262144;
    f16* wih1 = w16 + 4 * 262144;

    (void)hipFuncSetAttribute(reinterpret_cast<const void*>(k_rec),
                              hipFuncAttributeMaxDynamicSharedMemorySize, 155648);

    P6 p { (const float*)d_in[11], (const float*)d_in[17],   // nl_Whh0, nr_Whh0
           (const float*)d_in[14], (const float*)d_in[20],   // nl_Whh1, nr_Whh1
           (const float*)d_in[13], (const float*)d_in[19] }; // nl_Wih1, nr_Wih1
    k_wipe<<<1024, 256, 0, stream>>>((u64*)(ws + 3932160), 4325376L);  // ring+h0img
    k_cvt<<<6144, 256, 0, stream>>>(p, w16);
    k_scalar_lstm<<<512, 128, 0, stream>>>(ln, rn, tlW, tlU, tlb, trW, trU, trb, states);
    k_rec<<<256, 384, 155648, stream>>>(states, whh0, whh1, wih1, wih0L, wih0R,
                                        b0L, b0R, b1L, b1R, h0img, ring, h1out);
    k_mlp<<<256, 256, 0, stream>>>(h1out, mW1, mb1, mW2, mb2, (float*)d_out);
}

// Round 13
// 722.715 us; speedup vs baseline: 1.2570x; 1.2570x over previous
//
#include <hip/hip_runtime.h>

// VoiceModel: 2 branches x { scalar-LSTM(1->1,L2) over T=512 per (b,class),
// then LSTM(1->256,L2) over 128 class-steps }, concat -> MLP(512->200->128).
// Round 13: L0/L1 pipelined across 512 blocks in ONE launch. Blocks 0-255 run
// layer 0 (round-9 k_rec0, slimmed to 78 KB LDS); blocks 256-511 run layer 1
// (4 waves, Whh1 in LDS + Wih1 streamed from L2), lag-1 consuming h0img via
// R0's monotonic flags. Exchange protocol = round-9 proven relaxed-sc1 + flag.
// Deadlock-free under any block scheduling (graceful sequential fallback).

typedef _Float16 f16;
typedef __attribute__((ext_vector_type(4))) _Float16 f16x4;
typedef __attribute__((ext_vector_type(8))) _Float16 f16x8;
typedef __attribute__((ext_vector_type(4))) float f32x4;
typedef unsigned long long u64;

#define NBATCH 256
#define NTIME  512
#define NCLS   128
#define NHID   256

__device__ __forceinline__ float sigf(float x) {
    return __builtin_amdgcn_rcpf(1.0f + __expf(-x));
}
__device__ __forceinline__ float tanh_f(float x) {
    return fmaf(2.0f, __builtin_amdgcn_rcpf(1.0f + __expf(-2.0f * x)), -1.0f);
}
__device__ __forceinline__ f16x4 LO(f16x8 v) { f16x4 r; r[0]=v[0]; r[1]=v[1]; r[2]=v[2]; r[3]=v[3]; return r; }
__device__ __forceinline__ f16x4 HI(f16x8 v) { f16x4 r; r[0]=v[4]; r[1]=v[5]; r[2]=v[6]; r[3]=v[7]; return r; }

// LLC-coherent (sc1) relaxed agent atomics (proven round 9).
__device__ __forceinline__ u64 ld_llc(const u64* p) {
    return __hip_atomic_load(p, __ATOMIC_RELAXED, __HIP_MEMORY_SCOPE_AGENT);
}
__device__ __forceinline__ void st_llc(u64* p, u64 v) {
    __hip_atomic_store(p, v, __ATOMIC_RELAXED, __HIP_MEMORY_SCOPE_AGENT);
}
__device__ __forceinline__ int ld_flag(const int* p) {
    return __hip_atomic_load(p, __ATOMIC_RELAXED, __HIP_MEMORY_SCOPE_AGENT);
}
__device__ __forceinline__ void st_flag(int* p, int v) {
    __hip_atomic_store(p, v, __ATOMIC_RELAXED, __HIP_MEMORY_SCOPE_AGENT);
}

// ---------------- K0: convert + swizzle 6 weight matrices (1024x256) to f16 --
// layout per matrix: elem ((g*16+fi)*8+ktp)*512 + l*8 + e   (l = lane)
//   = W[g*256 + fi*16 + fr][ktp*32 + (e>>2)*16 + fq*4 + (e&3)]
struct P6 {
    const float* s0; const float* s1; const float* s2;
    const float* s3; const float* s4; const float* s5;
};

__global__ __launch_bounds__(256) void k_cvt(P6 p, f16* __restrict__ dst) {
    int i = blockIdx.x * 256 + threadIdx.x;      // 6 * 262144 total
    int seg = i >> 18, d = i & 262143;
    const float* s = seg == 0 ? p.s0 : seg == 1 ? p.s1 : seg == 2 ? p.s2
                   : seg == 3 ? p.s3 : seg == 4 ? p.s4 : p.s5;
    const int e  = d & 7;
    const int fr = (d >> 3) & 15;
    const int fq = (d >> 7) & 3;
    const int ktp = (d >> 9) & 7;
    const int fi = (d >> 12) & 15;
    const int g  = (d >> 16) & 3;
    const int row = g * 256 + fi * 16 + fr;
    const int col = ktp * 32 + (e >> 2) * 16 + fq * 4 + (e & 3);
    dst[i] = (f16)s[row * 256 + col];
}

// ---------------- zero the exchange flags (every call; graph-replay safe) ----
__global__ void k_zero(int* __restrict__ f) { f[blockIdx.x * 1024 + threadIdx.x] = 0; }

// ---------------- K1: scalar 2-layer LSTM per (branch, b, class) -------------
__global__ __launch_bounds__(128) void k_scalar_lstm(
    const int* __restrict__ ln, const int* __restrict__ rn,
    const float* __restrict__ tlW, const float* __restrict__ tlU, const float* __restrict__ tlb,
    const float* __restrict__ trW, const float* __restrict__ trU, const float* __restrict__ trb,
    float* __restrict__ states)
{
    __shared__ int tok[NTIME];
    const int bid = blockIdx.x;
    const int branch = bid >> 8;
    const int b = bid & 255;
    const int* tp = (branch ? rn : ln) + (size_t)b * (4 * NTIME);  // voice 0
    for (int i = threadIdx.x; i < NTIME; i += 128) tok[i] = tp[i];
    __syncthreads();
    const float* W  = branch ? trW : tlW;
    const float* U  = branch ? trU : tlU;
    const float* Bb = branch ? trb : tlb;
    const float u00 = U[0], u01 = U[1], u02 = U[2], u03 = U[3];
    const float f00 = Bb[0], f01 = Bb[1], f02 = Bb[2], f03 = Bb[3];
    const float o00 = f00 + W[0], o01 = f01 + W[1], o02 = f02 + W[2], o03 = f03 + W[3];
    const float w10 = W[4], w11 = W[5], w12 = W[6], w13 = W[7];
    const float u10 = U[4], u11 = U[5], u12 = U[6], u13 = U[7];
    const float b10 = Bb[4], b11 = Bb[5], b12 = Bb[6], b13 = Bb[7];
    const int n = threadIdx.x;
    float h0 = 0.f, c0 = 0.f, h1 = 0.f, c1 = 0.f;
    for (int t = 0; t < NTIME; ++t) {
        const bool x = (tok[t] == n);
        float pi = fmaf(u00, h0, x ? o00 : f00);
        float pf = fmaf(u01, h0, x ? o01 : f01);
        float pg = fmaf(u02, h0, x ? o02 : f02);
        float po = fmaf(u03, h0, x ? o03 : f03);
        float ig = sigf(pi), fg = sigf(pf), gg = tanh_f(pg), og = sigf(po);
        c0 = fmaf(fg, c0, ig * gg);
        h0 = og * tanh_f(c0);
        pi = fmaf(w10, h0, fmaf(u10, h1, b10));
        pf = fmaf(w11, h0, fmaf(u11, h1, b11));
        pg = fmaf(w12, h0, fmaf(u12, h1, b12));
        po = fmaf(w13, h0, fmaf(u13, h1, b13));
        ig = sigf(pi); fg = sigf(pf); gg = tanh_f(pg); og = sigf(po);
        c1 = fmaf(fg, c1, ig * gg);
        h1 = og * tanh_f(c1);
    }
    states[((size_t)(branch * NBATCH + b)) * NCLS + n] = h1;
}

// ---------------- K2: pipelined L0+L1 recurrence (512 blocks) ----------------
// blocks 0-255: layer 0 (group g = bid&31, member qm = bid>>5). 4 waves = gates.
// blocks 256-511: layer 1 (same mapping on bid-256). 4 waves = gates; each wave
// computes Whh1 (LDS) + Wih1 (L2 stream) for both frags; wave 0 finishes.
// L1 consumes h0img[g][t] gated by flags0 (monotonic); lag-1 pipeline.
__global__ __launch_bounds__(256, 2) void k_rec(
    const float* __restrict__ states,
    const f16* __restrict__ whh0, const f16* __restrict__ whh1,
    const f16* __restrict__ wih1,
    const float* __restrict__ wih0L, const float* __restrict__ wih0R,
    const float* __restrict__ b0L, const float* __restrict__ b0R,
    const float* __restrict__ b1L, const float* __restrict__ b1R,
    f16* __restrict__ h0img,               // [32 group][128 s][4096]
    f16* __restrict__ ring,                // [32 group][4 slot][4096]
    int* __restrict__ flags0,              // [32 group][8] stride 64 ints
    int* __restrict__ flags1,              // [32 group][8] stride 64 ints
    float* __restrict__ h1out)             // [2][256][256] f32
{
    extern __shared__ char smem[];
    f16*   wlds = (f16*)smem;                    // 65536 B weight slice
    f16*   img  = (f16*)(smem + 65536);          // 8192 B h image
    float* cmb  = (float*)(smem + 73728);        // 6144 B  (total 79872)

    const int bid = blockIdx.x;
    const bool isL1 = bid >= 256;
    const int sub = isL1 ? (bid - 256) : bid;
    const int qm = sub >> 5, g = sub & 31;
    const int branch = g >> 4, tb = g & 15;
    const int tid = threadIdx.x;
    const int w = tid >> 6, l = tid & 63, fr = l & 15, fq = l >> 4;

    {   // stage the recurrent weight slice (Whh0 or Whh1): 64 rows x 512 f16
        const f16* base = (isL1 ? whh1 : whh0) + ((size_t)branch << 18);
        for (int c = tid; c < 4096; c += 256) {
            const int rl = c >> 6, coli = c & 63;
            const int gg = rl >> 4, ff = (rl >> 3) & 1, ktp = rl & 7;
            *(uint4*)(wlds + rl * 512 + coli * 8) =
                *(const uint4*)(base + ((size_t)((gg * 16 + qm * 2 + ff) * 8 + ktp) << 9) + coli * 8);
        }
    }
    ((uint4*)img)[tid] = (uint4){0u, 0u, 0u, 0u};
    ((uint4*)img)[tid + 256] = (uint4){0u, 0u, 0u, 0u};

    if (!isL1) {
        // ================= LAYER 0 =================
        const float* bias = branch ? b0R : b0L;
        const float* w0p  = branch ? wih0R : wih0L;
        const int fi_f = qm * 2 + (w < 2 ? w : 0);
        float bv[4], w0v[4];
#pragma unroll
        for (int g4 = 0; g4 < 4; ++g4) {
            bv[g4]  = bias[g4 * 256 + fi_f * 16 + fr];
            w0v[g4] = w0p[g4 * 256 + fi_f * 16 + fr];
        }
        float cst[4] = {0.f, 0.f, 0.f, 0.f};
        f16* gimg = h0img + (size_t)g * (NCLS * 4096);
        int* f0 = flags0 + g * 512;
        __syncthreads();

        for (int s = 0; s < NCLS; ++s) {
            float st[4];
            if (w < 2) {
#pragma unroll
                for (int r = 0; r < 4; ++r)
                    st[r] = states[((size_t)(branch * NBATCH + tb * 16 + fq * 4 + r)) * NCLS + s];
            }
            f16x4 af[16];
#pragma unroll
            for (int kt = 0; kt < 16; ++kt)
                af[kt] = *(const f16x4*)(img + kt * 256 + l * 4);
            f32x4 acc[2];
#pragma unroll
            for (int f = 0; f < 2; ++f) {
                f32x4 a0 = {0.f,0.f,0.f,0.f}, a1 = {0.f,0.f,0.f,0.f};
#pragma unroll
                for (int ktp = 0; ktp < 8; ++ktp) {
                    const f16x8 v = *(const f16x8*)(wlds + (((w * 2 + f) * 8 + ktp) << 9) + l * 8);
                    a0 = __builtin_amdgcn_mfma_f32_16x16x16f16(af[2 * ktp],     LO(v), a0, 0, 0, 0);
                    a1 = __builtin_amdgcn_mfma_f32_16x16x16f16(af[2 * ktp + 1], HI(v), a1, 0, 0, 0);
                }
                acc[f] = a0 + a1;
            }
            // publish: e0=(w0,f1) e1=(w1,f0) e2=(w2,f0) e3=(w2,f1) e4=(w3,f0) e5=(w3,f1)
            if (w == 0) {
#pragma unroll
                for (int r = 0; r < 4; ++r) cmb[(0 * 4 + r) * 64 + l] = acc[1][r];
            } else if (w == 1) {
#pragma unroll
                for (int r = 0; r < 4; ++r) cmb[(1 * 4 + r) * 64 + l] = acc[0][r];
            } else if (w == 2) {
#pragma unroll
                for (int r = 0; r < 4; ++r) {
                    cmb[(2 * 4 + r) * 64 + l] = acc[0][r];
                    cmb[(3 * 4 + r) * 64 + l] = acc[1][r];
                }
            } else {
#pragma unroll
                for (int r = 0; r < 4; ++r) {
                    cmb[(4 * 4 + r) * 64 + l] = acc[0][r];
                    cmb[(5 * 4 + r) * 64 + l] = acc[1][r];
                }
            }
            __syncthreads();                // cmb ready; img reads done
            if (w < 2) {                    // finisher: frag f = w
#pragma unroll
                for (int r = 0; r < 4; ++r) {
                    const float g0 = (w == 0) ? acc[0][r] : cmb[(0 * 4 + r) * 64 + l];
                    const float g1 = (w == 0) ? cmb[(1 * 4 + r) * 64 + l] : acc[1][r];
                    const float g2 = (w == 0) ? cmb[(2 * 4 + r) * 64 + l] : cmb[(3 * 4 + r) * 64 + l];
                    const float g3 = (w == 0) ? cmb[(4 * 4 + r) * 64 + l] : cmb[(5 * 4 + r) * 64 + l];
                    const float pi = fmaf(st[r], w0v[0], g0 + bv[0]);
                    const float pf = fmaf(st[r], w0v[1], g1 + bv[1]);
                    const float pg = fmaf(st[r], w0v[2], g2 + bv[2]);
                    const float po = fmaf(st[r], w0v[3], g3 + bv[3]);
                    const float ig = sigf(pi), fg = sigf(pf), gg = tanh_f(pg), og = sigf(po);
                    cst[r] = fmaf(fg, cst[r], ig * gg);
                    const float hn = og * tanh_f(cst[r]);
                    img[fi_f * 256 + (fq * 4 + r + 16 * (fr >> 2)) * 4 + (fr & 3)] = (f16)hn;
                }
            }
            __syncthreads();                // own 1 KB chunk complete in LDS
            if (w == 0) {
                u64* gd = (u64*)(gimg + (size_t)s * 4096);
                st_llc(gd + qm * 128 + l,      ((const u64*)img)[qm * 128 + l]);
                st_llc(gd + qm * 128 + 64 + l, ((const u64*)img)[qm * 128 + 64 + l]);
                asm volatile("s_waitcnt vmcnt(0)" ::: "memory");
                if (l == 0) st_flag(f0 + qm * 64, s + 1);
                if (s < NCLS - 1 && l < 7) {
                    const int p = l + (l >= qm);
                    while (ld_flag(f0 + p * 64) <= s) __builtin_amdgcn_s_sleep(1);
                }
            }
            if (s == NCLS - 1) break;
            __syncthreads();                // peers ready
            if (tid < 128) {
                const u64* gs = (const u64*)(gimg + (size_t)s * 4096);
                u64 tmp[7];
#pragma unroll
                for (int j = 0; j < 7; ++j) {
                    const int p = j + (j >= qm);
                    tmp[j] = ld_llc(gs + p * 128 + tid);
                }
#pragma unroll
                for (int j = 0; j < 7; ++j) {
                    const int p = j + (j >= qm);
                    ((u64*)img)[p * 128 + tid] = tmp[j];
                }
            }
            __syncthreads();                // img(s) complete
        }
    } else {
        // ================= LAYER 1 =================
        const float* bias = branch ? b1R : b1L;
        float bv[2][4];
#pragma unroll
        for (int f = 0; f < 2; ++f)
#pragma unroll
            for (int g4 = 0; g4 < 4; ++g4)
                bv[f][g4] = bias[g4 * 256 + (qm * 2 + f) * 16 + fr];
        float cst[2][4] = {{0.f,0.f,0.f,0.f},{0.f,0.f,0.f,0.f}};
        const f16* wstream = wih1 + ((size_t)branch << 18) + l * 8;
        const f16* gimg = h0img + (size_t)g * (NCLS * 4096);
        f16* gring = ring + (size_t)g * (4 * 4096);
        int* f0 = flags0 + g * 512;
        int* f1 = flags1 + g * 512;
        __syncthreads();
        if (w == 1 && l < 8) {              // wait for h0(0) (all 8 producers)
            while (ld_flag(f0 + l * 64) < 1) __builtin_amdgcn_s_sleep(2);
        }
        __syncthreads();
        f16x4 af0[16];
        {
            const u64* s2 = (const u64*)gimg + l;
#pragma unroll
            for (int kt = 0; kt < 16; ++kt)
                af0[kt] = __builtin_bit_cast(f16x4, ld_llc(s2 + kt * 64));
        }

        for (int t = 0; t < NCLS; ++t) {
            // stream Wih1 fragments (loop-invariant rows; L2-resident), issue early
            f16x8 wv[2][8];
#pragma unroll
            for (int f = 0; f < 2; ++f)
#pragma unroll
                for (int ktp = 0; ktp < 8; ++ktp)
                    wv[f][ktp] = *(const f16x8*)(wstream
                        + ((size_t)((w * 16 + qm * 2 + f) * 8 + ktp) << 9));
            f16x4 af1[16];
#pragma unroll
            for (int kt = 0; kt < 16; ++kt)
                af1[kt] = *(const f16x4*)(img + kt * 256 + l * 4);
            f32x4 acc[2];
#pragma unroll
            for (int f = 0; f < 2; ++f) {
                f32x4 a0 = {0.f,0.f,0.f,0.f}, a1 = {0.f,0.f,0.f,0.f};
#pragma unroll
                for (int ktp = 0; ktp < 8; ++ktp) {
                    const f16x8 v = *(const f16x8*)(wlds + (((w * 2 + f) * 8 + ktp) << 9) + l * 8);
                    a0 = __builtin_amdgcn_mfma_f32_16x16x16f16(af1[2 * ktp],     LO(v), a0, 0, 0, 0);
                    a1 = __builtin_amdgcn_mfma_f32_16x16x16f16(af1[2 * ktp + 1], HI(v), a1, 0, 0, 0);
                }
#pragma unroll
                for (int ktp = 0; ktp < 8; ++ktp) {
                    a0 = __builtin_amdgcn_mfma_f32_16x16x16f16(af0[2 * ktp],     LO(wv[f][ktp]), a0, 0, 0, 0);
                    a1 = __builtin_amdgcn_mfma_f32_16x16x16f16(af0[2 * ktp + 1], HI(wv[f][ktp]), a1, 0, 0, 0);
                }
                acc[f] = a0 + a1;
            }
            if (w > 0) {                    // publish: e = (w-1)*2+f
#pragma unroll
                for (int f = 0; f < 2; ++f)
#pragma unroll
                    for (int r = 0; r < 4; ++r)
                        cmb[(((w - 1) * 2 + f) * 4 + r) * 64 + l] = acc[f][r];
            }
            __syncthreads();                // cmb ready; img reads done
            if (w == 0) {                   // finisher: both frags
#pragma unroll
                for (int f = 0; f < 2; ++f) {
#pragma unroll
                    for (int r = 0; r < 4; ++r) {
                        const float g0 = acc[f][r];
                        const float g1 = cmb[((0 * 2 + f) * 4 + r) * 64 + l];
                        const float g2 = cmb[((1 * 2 + f) * 4 + r) * 64 + l];
                        const float g3 = cmb[((2 * 2 + f) * 4 + r) * 64 + l];
                        const float pi = g0 + bv[f][0];
                        const float pf = g1 + bv[f][1];
                        const float pg = g2 + bv[f][2];
                        const float po = g3 + bv[f][3];
                        const float ig = sigf(pi), fg = sigf(pf), gg = tanh_f(pg), og = sigf(po);
                        cst[f][r] = fmaf(fg, cst[f][r], ig * gg);
                        const float hn = og * tanh_f(cst[f][r]);
                        if (t == NCLS - 1)
                            h1out[((size_t)(branch * NBATCH + tb * 16 + fq * 4 + r)) * NHID
                                  + (qm * 2 + f) * 16 + fr] = hn;
                        else
                            img[(qm * 2 + f) * 256 + (fq * 4 + r + 16 * (fr >> 2)) * 4 + (fr & 3)] = (f16)hn;
                    }
                }
            }
            if (t == NCLS - 1) break;
            f16* slot = gring + (size_t)(t & 3) * 4096;
            if (w == 0) {                   // push own chunk (own-wave writes)
                asm volatile("s_waitcnt lgkmcnt(0)" ::: "memory");
                u64* gd = (u64*)slot;
                st_llc(gd + qm * 128 + l,      ((const u64*)img)[qm * 128 + l]);
                st_llc(gd + qm * 128 + 64 + l, ((const u64*)img)[qm * 128 + 64 + l]);
                asm volatile("s_waitcnt vmcnt(0)" ::: "memory");
                if (l == 0) st_flag(f1 + qm * 64, t + 1);
                if (l < 7) {
                    const int p = l + (l >= qm);
                    while (ld_flag(f1 + p * 64) <= t) __builtin_amdgcn_s_sleep(1);
                }
            }
            if (w == 1 && l < 8) {          // h0(t+1) ready? (flags0 monotonic)
                while (ld_flag(f0 + l * 64) < t + 2) __builtin_amdgcn_s_sleep(1);
            }
            __syncthreads();                // peers + h0(t+1) ready
            {                               // prefetch h0(t+1) frags (all waves)
                const u64* s2 = (const u64*)(gimg + (size_t)(t + 1) * 4096) + l;
#pragma unroll
                for (int kt = 0; kt < 16; ++kt)
                    af0[kt] = __builtin_bit_cast(f16x4, ld_llc(s2 + kt * 64));
            }
            if (tid < 128) {                // gather peers' h1(t)
                const u64* gs = (const u64*)slot;
                u64 tmp[7];
#pragma unroll
                for (int j = 0; j < 7; ++j) {
                    const int p = j + (j >= qm);
                    tmp[j] = ld_llc(gs + p * 128 + tid);
                }
#pragma unroll
                for (int j = 0; j < 7; ++j) {
                    const int p = j + (j >= qm);
                    ((u64*)img)[p * 128 + tid] = tmp[j];
                }
            }
            __syncthreads();                // img(t) complete
        }
    }
}

// ---------------- K4: MLP head (2H -> 200 -> 128), f32 ------------------------
__global__ __launch_bounds__(256) void k_mlp(
    const float* __restrict__ h1all,   // [2][256][256]
    const float* __restrict__ W1, const float* __restrict__ b1,
    const float* __restrict__ W2, const float* __restrict__ b2,
    float* __restrict__ out)
{
    __shared__ float hrow[512];
    __shared__ float hid[200];
    const int b = blockIdx.x, tid = threadIdx.x;
    hrow[tid]       = h1all[(size_t)b * NHID + tid];
    hrow[256 + tid] = h1all[(size_t)(NBATCH + b) * NHID + tid];
    __syncthreads();
    if (tid < 200) {
        float a = b1[tid];
        const float* wr = W1 + (size_t)tid * 512;
        for (int k = 0; k < 512; ++k) a = fmaf(wr[k], hrow[k], a);
        hid[tid] = fmaxf(a, 0.f);
    }
    __syncthreads();
    if (tid < 128) {
        float a = b2[tid];
        const float* wr = W2 + (size_t)tid * 200;
        for (int j = 0; j < 200; ++j) a = fmaf(wr[j], hid[j], a);
        out[(size_t)b * 128 + tid] = a;
    }
}

// ---------------- launch ------------------------------------------------------
extern "C" void kernel_launch(void* const* d_in, const int* in_sizes, int n_in,
                              void* d_out, int out_size, void* d_ws, size_t ws_size,
                              hipStream_t stream)
{
    (void)in_sizes; (void)n_in; (void)out_size; (void)ws_size;
    const int*   ln    = (const int*)d_in[0];
    const int*   rn    = (const int*)d_in[2];
    const float* tlW   = (const float*)d_in[4];
    const float* tlU   = (const float*)d_in[5];
    const float* tlb   = (const float*)d_in[6];
    const float* trW   = (const float*)d_in[7];
    const float* trU   = (const float*)d_in[8];
    const float* trb   = (const float*)d_in[9];
    const float* wih0L = (const float*)d_in[10];
    const float* b0L   = (const float*)d_in[12];
    const float* b1L   = (const float*)d_in[15];
    const float* wih0R = (const float*)d_in[16];
    const float* b0R   = (const float*)d_in[18];
    const float* b1R   = (const float*)d_in[21];
    const float* mW1   = (const float*)d_in[22];
    const float* mb1   = (const float*)d_in[23];
    const float* mW2   = (const float*)d_in[24];
    const float* mb2   = (const float*)d_in[25];

    // workspace layout (bytes)
    char* ws = (char*)d_ws;
    f16*   w16    = (f16*)ws;                        // 3 MB swizzled weights
    float* states = (float*)(ws + 3145728);          // 256 KB
    float* h1out  = (float*)(ws + 3407872);          // 512 KB
    int*   flags  = (int*)(ws + 3932160);            // 128 KB (2 x 32 x 8 x 64 ints)
    f16*   ring   = (f16*)(ws + 4063232);            // 1 MB (32 x 4 x 4096 f16)
    f16*   h0img  = (f16*)(ws + 5111808);            // 32 MB (32 x 128 x 4096 f16)

    f16* whh0 = w16;
    f16* whh1 = w16 + 2 * 262144;
    f16* wih1 = w16 + 4 * 262144;
    int* flags0 = flags;
    int* flags1 = flags + 16384;

    (void)hipFuncSetAttribute(reinterpret_cast<const void*>(k_rec),
                              hipFuncAttributeMaxDynamicSharedMemorySize, 79872);

    P6 p { (const float*)d_in[11], (const float*)d_in[17],   // nl_Whh0, nr_Whh0
           (const float*)d_in[14], (const float*)d_in[20],   // nl_Whh1, nr_Whh1
           (const float*)d_in[13], (const float*)d_in[19] }; // nl_Wih1, nr_Wih1
    k_zero<<<32, 1024, 0, stream>>>(flags);
    k_cvt<<<6144, 256, 0, stream>>>(p, w16);
    k_scalar_lstm<<<512, 128, 0, stream>>>(ln, rn, tlW, tlU, tlb, trW, trU, trb, states);
    k_rec<<<512, 256, 79872, stream>>>(states, whh0, whh1, wih1, wih0L, wih0R,
                                       b0L, b0R, b1L, b1R, h0img, ring,
                                       flags0, flags1, h1out);
    k_mlp<<<256, 256, 0, stream>>>(h1out, mW1, mb1, mW2, mb2, (float*)d_out);
}